// Round 1
// baseline (396.006 us; speedup 1.0000x reference)
//
#include <hip/hip_runtime.h>
#include <hip/hip_bf16.h>
#include <math.h>

#define S_TOK 8192
#define M_DIM 1024
#define E_NUM 8
#define F_DIM 4096
#define CAP   1024

typedef short short8 __attribute__((ext_vector_type(8)));
typedef float f32x4 __attribute__((ext_vector_type(4)));
typedef unsigned short ushortx4 __attribute__((ext_vector_type(4)));

__device__ inline unsigned short f2bf(float f) {
    union { float f; unsigned int u; } v; v.f = f;
    unsigned int r = v.u + 0x7fffu + ((v.u >> 16) & 1u);
    return (unsigned short)(r >> 16);
}

__device__ inline float gelu_tanh(float x) {
    const float c = 0.7978845608028654f;
    float t = tanhf(c * (x + 0.044715f * x * x * x));
    return 0.5f * x * (1.0f + t);
}

__device__ inline void gl_lds16(const void* g, void* l) {
    __builtin_amdgcn_global_load_lds(
        (const __attribute__((address_space(1))) unsigned int*)g,
        (__attribute__((address_space(3))) unsigned int*)l, 16, 0, 0);
}

// ---------------- gating: logits (fp64 accum) -> argmax + softmax prob ----------------
__global__ __launch_bounds__(256) void gating_kernel(
    const float* __restrict__ x, const float* __restrict__ wg,
    int* __restrict__ idx, float* __restrict__ gate)
{
    int wid = threadIdx.x >> 6;
    int lane = threadIdx.x & 63;
    int s = blockIdx.x * 4 + wid;
    const float* xs = x + (size_t)s * M_DIM;

    double acc[E_NUM];
#pragma unroll
    for (int e = 0; e < E_NUM; e++) acc[e] = 0.0;

    for (int i = lane; i < M_DIM; i += 64) {
        float xv = xs[i];
        float4 wa = *(const float4*)(wg + (size_t)i * E_NUM);
        float4 wb = *(const float4*)(wg + (size_t)i * E_NUM + 4);
        acc[0] += (double)xv * (double)wa.x;
        acc[1] += (double)xv * (double)wa.y;
        acc[2] += (double)xv * (double)wa.z;
        acc[3] += (double)xv * (double)wa.w;
        acc[4] += (double)xv * (double)wb.x;
        acc[5] += (double)xv * (double)wb.y;
        acc[6] += (double)xv * (double)wb.z;
        acc[7] += (double)xv * (double)wb.w;
    }
#pragma unroll
    for (int e = 0; e < E_NUM; e++) {
        double v = acc[e];
        for (int o = 32; o > 0; o >>= 1) v += __shfl_down(v, o, 64);
        acc[e] = v;
    }
    if (lane == 0) {
        double mx = acc[0]; int am = 0;
#pragma unroll
        for (int e = 1; e < E_NUM; e++) {
            if (acc[e] > mx) { mx = acc[e]; am = e; }
        }
        double se = 0.0;
#pragma unroll
        for (int e = 0; e < E_NUM; e++) se += exp(acc[e] - mx);
        idx[s] = am;
        gate[s] = (float)(1.0 / se);
    }
}

// ---------------- scan: token-order positions per expert, capacity drop, slot map ----------------
__global__ __launch_bounds__(1024) void scan_build(
    const int* __restrict__ idx, int* __restrict__ srcmap)
{
    // packed scan: 4 uints, each holding two 16-bit expert counters (max 8192 < 65536, no carry)
    __shared__ unsigned int sc[2][4][1024];
    int t = threadIdx.x;

    // init srcmap to -1
    for (int i = t; i < E_NUM * CAP; i += 1024) srcmap[i] = -1;

    int eid[8];
    unsigned int cnt[E_NUM];
#pragma unroll
    for (int e = 0; e < E_NUM; e++) cnt[e] = 0;
#pragma unroll
    for (int i = 0; i < 8; i++) {
        int e = idx[t * 8 + i];
        eid[i] = e;
        cnt[e]++;
    }
    unsigned int pk[4];
#pragma unroll
    for (int i = 0; i < 4; i++) pk[i] = cnt[2 * i] | (cnt[2 * i + 1] << 16);
#pragma unroll
    for (int i = 0; i < 4; i++) sc[0][i][t] = pk[i];

    int buf = 0;
    for (int ofs = 1; ofs < 1024; ofs <<= 1) {
        __syncthreads();
        unsigned int v[4];
#pragma unroll
        for (int i = 0; i < 4; i++) {
            v[i] = sc[buf][i][t] + ((t >= ofs) ? sc[buf][i][t - ofs] : 0u);
            sc[buf ^ 1][i][t] = v[i];
        }
        buf ^= 1;
    }
    __syncthreads();
    unsigned int pos[E_NUM];
#pragma unroll
    for (int e = 0; e < E_NUM; e++) {
        unsigned int incl = (sc[buf][e >> 1][t] >> ((e & 1) * 16)) & 0xffffu;
        pos[e] = incl - cnt[e]; // exclusive start for this thread's chunk
    }
#pragma unroll
    for (int i = 0; i < 8; i++) {
        int e = eid[i];
        unsigned int p = pos[e]++;
        if (p < CAP) srcmap[e * CAP + p] = t * 8 + i;
    }
}

// ---------------- dispatch: gather token rows -> bf16 A1 [E*C][M] ----------------
__global__ __launch_bounds__(256) void dispatch_kernel(
    const float* __restrict__ x, const int* __restrict__ srcmap,
    unsigned short* __restrict__ A1)
{
    int slot = blockIdx.x;
    int s = srcmap[slot];
    int t = threadIdx.x;
    ushortx4 o;
    if (s >= 0) {
        float4 v = ((const float4*)(x + (size_t)s * M_DIM))[t];
        o[0] = f2bf(v.x); o[1] = f2bf(v.y); o[2] = f2bf(v.z); o[3] = f2bf(v.w);
    } else {
        o[0] = 0; o[1] = 0; o[2] = 0; o[3] = 0;
    }
    ((ushortx4*)(A1 + (size_t)slot * M_DIM))[t] = o;
}

// ---------------- transpose + fp32->bf16: out[e][c][r] = in[e][r][c] ----------------
__global__ __launch_bounds__(256) void transpose_cvt(
    const float* __restrict__ in, unsigned short* __restrict__ out, int R, int Cc)
{
    __shared__ float tile[32][33];
    int e = blockIdx.z;
    int br = blockIdx.y * 32, bc = blockIdx.x * 32;
    const float* ine = in + (size_t)e * R * Cc;
    unsigned short* oute = out + (size_t)e * R * Cc;
    int tx = threadIdx.x, ty = threadIdx.y;
#pragma unroll
    for (int i = 0; i < 32; i += 8)
        tile[ty + i][tx] = ine[(size_t)(br + ty + i) * Cc + (bc + tx)];
    __syncthreads();
#pragma unroll
    for (int i = 0; i < 32; i += 8)
        oute[(size_t)(bc + ty + i) * R + (br + tx)] = f2bf(tile[tx][ty + i]);
}

// ---------------- bf16 MFMA GEMM: C[128x128] tiles, BK=32, 4 waves ----------------
// A: [E][RA][K] bf16 row-major, B: [E][NB][K] bf16 row-major (i.e. B^T layout)
// MODE 0: OutH[e][r][c] = bf16(gelu(acc + bias[e][c]))
// MODE 1: s = srcmap[e*RA+r]; if s>=0: OutF[s][c] = gate[s]*(acc + bias[e][c])
template <int MODE>
__global__ __launch_bounds__(256) void gemm_bf16(
    const unsigned short* __restrict__ A, const unsigned short* __restrict__ B,
    const float* __restrict__ bias, float* __restrict__ OutF,
    unsigned short* __restrict__ OutH,
    const int* __restrict__ srcmap, const float* __restrict__ gate,
    int K, int RA, int NB, int tilesM, int tilesN)
{
    __shared__ __align__(16) unsigned short As[128 * 32];
    __shared__ __align__(16) unsigned short Bs[128 * 32];

    int bid = blockIdx.x;
    int tpe = tilesM * tilesN;
    int e = bid / tpe;
    int rem = bid - e * tpe;
    int tm = rem / tilesN;
    int tn = rem - tm * tilesN;

    const unsigned short* Ae = A + ((size_t)e * RA + (size_t)tm * 128) * K;
    const unsigned short* Be = B + ((size_t)e * NB + (size_t)tn * 128) * K;

    int tid = threadIdx.x;
    int wid = tid >> 6, lane = tid & 63;
    int srow = wid * 32 + (lane >> 2);   // 0..127 (staging row)
    int schunk = (lane & 3) * 8;         // bf16 element offset within row

    int fr = lane & 15, fk = (lane >> 4) * 8;
    int r0 = (wid >> 1) * 64, c0 = (wid & 1) * 64;

    f32x4 acc[4][4];
#pragma unroll
    for (int i = 0; i < 4; i++)
#pragma unroll
        for (int j = 0; j < 4; j++) acc[i][j] = (f32x4){0.f, 0.f, 0.f, 0.f};

    for (int k0 = 0; k0 < K; k0 += 32) {
        const unsigned short* ga = Ae + (size_t)srow * K + k0 + schunk;
        const unsigned short* gb = Be + (size_t)srow * K + k0 + schunk;
        gl_lds16(ga, &As[srow * 32 + schunk]);
        gl_lds16(ga + (size_t)16 * K, &As[(srow + 16) * 32 + schunk]);
        gl_lds16(gb, &Bs[srow * 32 + schunk]);
        gl_lds16(gb + (size_t)16 * K, &Bs[(srow + 16) * 32 + schunk]);
        asm volatile("s_waitcnt vmcnt(0)" ::: "memory");
        __syncthreads();

        short8 a[4], b[4];
#pragma unroll
        for (int mi = 0; mi < 4; mi++)
            a[mi] = *(const short8*)&As[(r0 + mi * 16 + fr) * 32 + fk];
#pragma unroll
        for (int ni = 0; ni < 4; ni++)
            b[ni] = *(const short8*)&Bs[(c0 + ni * 16 + fr) * 32 + fk];
#pragma unroll
        for (int mi = 0; mi < 4; mi++)
#pragma unroll
            for (int ni = 0; ni < 4; ni++)
                acc[mi][ni] = __builtin_amdgcn_mfma_f32_16x16x32_bf16(
                    a[mi], b[ni], acc[mi][ni], 0, 0, 0);
        __syncthreads();
    }

    int orow = (lane >> 4) * 4, ocol = lane & 15;
    if (MODE == 0) {
#pragma unroll
        for (int mi = 0; mi < 4; mi++) {
#pragma unroll
            for (int j = 0; j < 4; j++) {
                int r = tm * 128 + r0 + mi * 16 + orow + j;
                size_t rowbase = ((size_t)e * RA + r) * NB;
#pragma unroll
                for (int ni = 0; ni < 4; ni++) {
                    int c = tn * 128 + c0 + ni * 16 + ocol;
                    float v = acc[mi][ni][j] + bias[e * NB + c];
                    OutH[rowbase + c] = f2bf(gelu_tanh(v));
                }
            }
        }
    } else {
#pragma unroll
        for (int mi = 0; mi < 4; mi++) {
#pragma unroll
            for (int j = 0; j < 4; j++) {
                int r = tm * 128 + r0 + mi * 16 + orow + j;
                int slot = e * RA + r;
                int s = srcmap[slot];
                if (s < 0) continue;
                float g = gate[s];
                size_t rowbase = (size_t)s * NB;
#pragma unroll
                for (int ni = 0; ni < 4; ni++) {
                    int c = tn * 128 + c0 + ni * 16 + ocol;
                    OutF[rowbase + c] = g * (acc[mi][ni][j] + bias[e * NB + c]);
                }
            }
        }
    }
}

extern "C" void kernel_launch(void* const* d_in, const int* in_sizes, int n_in,
                              void* d_out, int out_size, void* d_ws, size_t ws_size,
                              hipStream_t stream) {
    const float* x  = (const float*)d_in[0];  // [S, M]
    const float* wg = (const float*)d_in[1];  // [M, E]
    const float* w1 = (const float*)d_in[2];  // [E, M, F]
    const float* b1 = (const float*)d_in[3];  // [E, F]
    const float* w2 = (const float*)d_in[4];  // [E, F, M]
    const float* b2 = (const float*)d_in[5];  // [E, M]
    float* out = (float*)d_out;

    char* ws = (char*)d_ws;
    unsigned short* A1  = (unsigned short*)(ws);                       // 16 MiB  [E*C][M]
    unsigned short* W1T = (unsigned short*)(ws + (size_t)(16u << 20)); // 64 MiB  [E][F][M]
    unsigned short* W2T = (unsigned short*)(ws + (size_t)(80u << 20)); // 64 MiB  [E][M][F]
    unsigned short* H   = (unsigned short*)(ws + (size_t)(144u << 20));// 64 MiB  [E][C][F]
    int*   idx  = (int*)(ws + (size_t)(208u << 20));
    float* gate = (float*)(ws + (size_t)(208u << 20) + 32768);
    int*   srcm = (int*)(ws + (size_t)(208u << 20) + 65536);

    hipMemsetAsync(d_out, 0, (size_t)S_TOK * M_DIM * sizeof(float), stream);

    gating_kernel<<<S_TOK / 4, 256, 0, stream>>>(x, wg, idx, gate);
    scan_build<<<1, 1024, 0, stream>>>(idx, srcm);
    dispatch_kernel<<<E_NUM * CAP, 256, 0, stream>>>(x, srcm, A1);
    transpose_cvt<<<dim3(F_DIM / 32, M_DIM / 32, E_NUM), dim3(32, 8), 0, stream>>>(
        w1, W1T, M_DIM, F_DIM);
    transpose_cvt<<<dim3(M_DIM / 32, F_DIM / 32, E_NUM), dim3(32, 8), 0, stream>>>(
        w2, W2T, F_DIM, M_DIM);

    // GEMM1: H = gelu(A1 @ w1 + b1)   [E][C=1024][F=4096], K=M=1024
    gemm_bf16<0><<<E_NUM * (CAP / 128) * (F_DIM / 128), 256, 0, stream>>>(
        A1, W1T, b1, nullptr, H, nullptr, nullptr,
        M_DIM, CAP, F_DIM, CAP / 128, F_DIM / 128);

    // GEMM2: out[s] = gate[s] * (H @ w2 + b2)  scatter, K=F=4096
    gemm_bf16<1><<<E_NUM * (CAP / 128) * (M_DIM / 128), 256, 0, stream>>>(
        H, W2T, b2, out, nullptr, srcm, gate,
        F_DIM, CAP, M_DIM, CAP / 128, M_DIM / 128);
}

// Round 2
// 375.797 us; speedup vs baseline: 1.0538x; 1.0538x over previous
//
#include <hip/hip_runtime.h>
#include <hip/hip_bf16.h>
#include <math.h>

#define S_TOK 8192
#define M_DIM 1024
#define E_NUM 8
#define F_DIM 4096
#define CAP   1024

typedef short short8 __attribute__((ext_vector_type(8)));
typedef float f32x4 __attribute__((ext_vector_type(4)));
typedef unsigned short ushortx4 __attribute__((ext_vector_type(4)));

__device__ inline unsigned short f2bf(float f) {
    union { float f; unsigned int u; } v; v.f = f;
    unsigned int r = v.u + 0x7fffu + ((v.u >> 16) & 1u);
    return (unsigned short)(r >> 16);
}

// gelu(x) = 0.5 x (1 + tanh(y)), y = c(x + 0.044715 x^3)
//         = x * e / (e + 1),  e = exp(2y) = exp2(2y*log2(e))   [1 v_exp_f32]
__device__ inline float gelu_fast(float x) {
    float y = 0.7978845608028654f * (x + 0.044715f * x * x * x);
    if (y > 40.f) return x;          // avoid inf/inf
    float e = exp2f(2.8853900817779268f * y);   // 2*log2(e)*y
    return x * e / (e + 1.0f);
}

__device__ inline void gl_lds16(const void* g, void* l) {
    __builtin_amdgcn_global_load_lds(
        (const __attribute__((address_space(1))) unsigned int*)g,
        (__attribute__((address_space(3))) unsigned int*)l, 16, 0, 0);
}

// ---------------- gating: logits (fp64 accum) -> argmax + softmax prob ----------------
__global__ __launch_bounds__(256) void gating_kernel(
    const float* __restrict__ x, const float* __restrict__ wg,
    int* __restrict__ idx, float* __restrict__ gate)
{
    int wid = threadIdx.x >> 6;
    int lane = threadIdx.x & 63;
    int s = blockIdx.x * 4 + wid;
    const float* xs = x + (size_t)s * M_DIM;

    double acc[E_NUM];
#pragma unroll
    for (int e = 0; e < E_NUM; e++) acc[e] = 0.0;

    for (int i = lane; i < M_DIM; i += 64) {
        float xv = xs[i];
        float4 wa = *(const float4*)(wg + (size_t)i * E_NUM);
        float4 wb = *(const float4*)(wg + (size_t)i * E_NUM + 4);
        acc[0] += (double)xv * (double)wa.x;
        acc[1] += (double)xv * (double)wa.y;
        acc[2] += (double)xv * (double)wa.z;
        acc[3] += (double)xv * (double)wa.w;
        acc[4] += (double)xv * (double)wb.x;
        acc[5] += (double)xv * (double)wb.y;
        acc[6] += (double)xv * (double)wb.z;
        acc[7] += (double)xv * (double)wb.w;
    }
#pragma unroll
    for (int e = 0; e < E_NUM; e++) {
        double v = acc[e];
        for (int o = 32; o > 0; o >>= 1) v += __shfl_down(v, o, 64);
        acc[e] = v;
    }
    if (lane == 0) {
        double mx = acc[0]; int am = 0;
#pragma unroll
        for (int e = 1; e < E_NUM; e++) {
            if (acc[e] > mx) { mx = acc[e]; am = e; }
        }
        double se = 0.0;
#pragma unroll
        for (int e = 0; e < E_NUM; e++) se += exp(acc[e] - mx);
        idx[s] = am;
        gate[s] = (float)(1.0 / se);
    }
}

// ---------------- scan: token-order positions per expert, capacity drop, slot map ----------------
__global__ __launch_bounds__(1024) void scan_build(
    const int* __restrict__ idx, int* __restrict__ srcmap)
{
    __shared__ unsigned int sc[2][4][1024];
    int t = threadIdx.x;

    for (int i = t; i < E_NUM * CAP; i += 1024) srcmap[i] = -1;

    int eid[8];
    unsigned int cnt[E_NUM];
#pragma unroll
    for (int e = 0; e < E_NUM; e++) cnt[e] = 0;
#pragma unroll
    for (int i = 0; i < 8; i++) {
        int e = idx[t * 8 + i];
        eid[i] = e;
        cnt[e]++;
    }
    unsigned int pk[4];
#pragma unroll
    for (int i = 0; i < 4; i++) pk[i] = cnt[2 * i] | (cnt[2 * i + 1] << 16);
#pragma unroll
    for (int i = 0; i < 4; i++) sc[0][i][t] = pk[i];

    int buf = 0;
    for (int ofs = 1; ofs < 1024; ofs <<= 1) {
        __syncthreads();
        unsigned int v[4];
#pragma unroll
        for (int i = 0; i < 4; i++) {
            v[i] = sc[buf][i][t] + ((t >= ofs) ? sc[buf][i][t - ofs] : 0u);
            sc[buf ^ 1][i][t] = v[i];
        }
        buf ^= 1;
    }
    __syncthreads();
    unsigned int pos[E_NUM];
#pragma unroll
    for (int e = 0; e < E_NUM; e++) {
        unsigned int incl = (sc[buf][e >> 1][t] >> ((e & 1) * 16)) & 0xffffu;
        pos[e] = incl - cnt[e];
    }
#pragma unroll
    for (int i = 0; i < 8; i++) {
        int e = eid[i];
        unsigned int p = pos[e]++;
        if (p < CAP) srcmap[e * CAP + p] = t * 8 + i;
    }
}

// ---------------- dispatch: gather token rows -> bf16 A1 [E*C][M] ----------------
__global__ __launch_bounds__(256) void dispatch_kernel(
    const float* __restrict__ x, const int* __restrict__ srcmap,
    unsigned short* __restrict__ A1)
{
    int slot = blockIdx.x;
    int s = srcmap[slot];
    int t = threadIdx.x;
    ushortx4 o;
    if (s >= 0) {
        float4 v = ((const float4*)(x + (size_t)s * M_DIM))[t];
        o[0] = f2bf(v.x); o[1] = f2bf(v.y); o[2] = f2bf(v.z); o[3] = f2bf(v.w);
    } else {
        o[0] = 0; o[1] = 0; o[2] = 0; o[3] = 0;
    }
    ((ushortx4*)(A1 + (size_t)slot * M_DIM))[t] = o;
}

// ---------------- transpose + fp32->bf16: out[e][c][r] = in[e][r][c] ----------------
__global__ __launch_bounds__(256) void transpose_cvt(
    const float* __restrict__ in, unsigned short* __restrict__ out, int R, int Cc)
{
    __shared__ float tile[32][33];
    int e = blockIdx.z;
    int br = blockIdx.y * 32, bc = blockIdx.x * 32;
    const float* ine = in + (size_t)e * R * Cc;
    unsigned short* oute = out + (size_t)e * R * Cc;
    int tx = threadIdx.x, ty = threadIdx.y;
#pragma unroll
    for (int i = 0; i < 32; i += 8)
        tile[ty + i][tx] = ine[(size_t)(br + ty + i) * Cc + (bc + tx)];
    __syncthreads();
#pragma unroll
    for (int i = 0; i < 32; i += 8)
        oute[(size_t)(bc + ty + i) * R + (br + tx)] = f2bf(tile[tx][ty + i]);
}

// ---------------- bf16 MFMA GEMM: 128x128 tiles, BK=32, 4 waves, double-buffered ----------------
// A: [E][RA][K] bf16 row-major, B: [E][NB][K] bf16 row-major (B^T layout)
// MODE 0: OutH[e][r][c] = bf16(gelu(acc + bias[e][c]))
// MODE 1: s = srcmap[e*RA+r]; if s>=0: OutF[s][c] = gate[s]*(acc + bias[e][c])
template <int MODE>
__global__ __launch_bounds__(256) void gemm_bf16(
    const unsigned short* __restrict__ A, const unsigned short* __restrict__ B,
    const float* __restrict__ bias, float* __restrict__ OutF,
    unsigned short* __restrict__ OutH,
    const int* __restrict__ srcmap, const float* __restrict__ gate,
    int K, int RA, int NB, int tilesM, int tilesN)
{
    __shared__ __align__(16) unsigned short As[2][128 * 32];
    __shared__ __align__(16) unsigned short Bs[2][128 * 32];

    int bid = blockIdx.x;
    int tpe = tilesM * tilesN;
    int e = bid / tpe;
    int rem = bid - e * tpe;
    int tm = rem / tilesN;
    int tn = rem - tm * tilesN;

    const unsigned short* Ae = A + ((size_t)e * RA + (size_t)tm * 128) * K;
    const unsigned short* Be = B + ((size_t)e * NB + (size_t)tn * 128) * K;

    int tid = threadIdx.x;
    int wid = tid >> 6, lane = tid & 63;
    int srow = wid * 32 + (lane >> 2);   // staging row (0..127 over 2 calls)
    int schunk = (lane & 3) * 8;         // bf16 elem offset within row

    int fr = lane & 15, fk = (lane >> 4) * 8;
    int r0 = (wid >> 1) * 64, c0 = (wid & 1) * 64;

#define STAGE(bufi, kk) do {                                                  \
    const unsigned short* ga = Ae + (size_t)srow * K + (kk) + schunk;         \
    const unsigned short* gb = Be + (size_t)srow * K + (kk) + schunk;         \
    gl_lds16(ga,                 &As[bufi][srow * 32 + schunk]);              \
    gl_lds16(ga + (size_t)16 * K, &As[bufi][(srow + 16) * 32 + schunk]);      \
    gl_lds16(gb,                 &Bs[bufi][srow * 32 + schunk]);              \
    gl_lds16(gb + (size_t)16 * K, &Bs[bufi][(srow + 16) * 32 + schunk]);      \
} while (0)

    f32x4 acc[4][4];
#pragma unroll
    for (int i = 0; i < 4; i++)
#pragma unroll
        for (int j = 0; j < 4; j++) acc[i][j] = (f32x4){0.f, 0.f, 0.f, 0.f};

    // prologue: stage tile 0
    STAGE(0, 0);
    asm volatile("s_waitcnt vmcnt(0)" ::: "memory");
    __syncthreads();

    int cur = 0;
    for (int k0 = 0; k0 < K; k0 += 32) {
        if (k0 + 32 < K) STAGE(cur ^ 1, k0 + 32);   // prefetch next tile (in flight over compute)

        short8 a[4], b[4];
#pragma unroll
        for (int mi = 0; mi < 4; mi++)
            a[mi] = *(const short8*)&As[cur][(r0 + mi * 16 + fr) * 32 + fk];
#pragma unroll
        for (int ni = 0; ni < 4; ni++)
            b[ni] = *(const short8*)&Bs[cur][(c0 + ni * 16 + fr) * 32 + fk];
#pragma unroll
        for (int mi = 0; mi < 4; mi++)
#pragma unroll
            for (int ni = 0; ni < 4; ni++)
                acc[mi][ni] = __builtin_amdgcn_mfma_f32_16x16x32_bf16(
                    a[mi], b[ni], acc[mi][ni], 0, 0, 0);

        asm volatile("s_waitcnt vmcnt(0)" ::: "memory");  // next tile landed
        __syncthreads();
        cur ^= 1;
    }
#undef STAGE

    int orow = (lane >> 4) * 4, ocol = lane & 15;
    if (MODE == 0) {
#pragma unroll
        for (int mi = 0; mi < 4; mi++) {
#pragma unroll
            for (int j = 0; j < 4; j++) {
                int r = tm * 128 + r0 + mi * 16 + orow + j;
                size_t rowbase = ((size_t)e * RA + r) * NB;
#pragma unroll
                for (int ni = 0; ni < 4; ni++) {
                    int c = tn * 128 + c0 + ni * 16 + ocol;
                    float v = acc[mi][ni][j] + bias[e * NB + c];
                    OutH[rowbase + c] = f2bf(gelu_fast(v));
                }
            }
        }
    } else {
#pragma unroll
        for (int mi = 0; mi < 4; mi++) {
#pragma unroll
            for (int j = 0; j < 4; j++) {
                int r = tm * 128 + r0 + mi * 16 + orow + j;
                int slot = e * RA + r;
                int s = srcmap[slot];
                if (s < 0) continue;
                float g = gate[s];
                size_t rowbase = (size_t)s * NB;
#pragma unroll
                for (int ni = 0; ni < 4; ni++) {
                    int c = tn * 128 + c0 + ni * 16 + ocol;
                    OutF[rowbase + c] = g * (acc[mi][ni][j] + bias[e * NB + c]);
                }
            }
        }
    }
}

extern "C" void kernel_launch(void* const* d_in, const int* in_sizes, int n_in,
                              void* d_out, int out_size, void* d_ws, size_t ws_size,
                              hipStream_t stream) {
    const float* x  = (const float*)d_in[0];  // [S, M]
    const float* wg = (const float*)d_in[1];  // [M, E]
    const float* w1 = (const float*)d_in[2];  // [E, M, F]
    const float* b1 = (const float*)d_in[3];  // [E, F]
    const float* w2 = (const float*)d_in[4];  // [E, F, M]
    const float* b2 = (const float*)d_in[5];  // [E, M]
    float* out = (float*)d_out;

    char* ws = (char*)d_ws;
    unsigned short* A1  = (unsigned short*)(ws);                       // 16 MiB  [E*C][M]
    unsigned short* W1T = (unsigned short*)(ws + (size_t)(16u << 20)); // 64 MiB  [E][F][M]
    unsigned short* W2T = (unsigned short*)(ws + (size_t)(80u << 20)); // 64 MiB  [E][M][F]
    unsigned short* H   = (unsigned short*)(ws + (size_t)(144u << 20));// 64 MiB  [E][C][F]
    int*   idx  = (int*)(ws + (size_t)(208u << 20));
    float* gate = (float*)(ws + (size_t)(208u << 20) + 32768);
    int*   srcm = (int*)(ws + (size_t)(208u << 20) + 65536);

    hipMemsetAsync(d_out, 0, (size_t)S_TOK * M_DIM * sizeof(float), stream);

    gating_kernel<<<S_TOK / 4, 256, 0, stream>>>(x, wg, idx, gate);
    scan_build<<<1, 1024, 0, stream>>>(idx, srcm);
    dispatch_kernel<<<E_NUM * CAP, 256, 0, stream>>>(x, srcm, A1);
    transpose_cvt<<<dim3(F_DIM / 32, M_DIM / 32, E_NUM), dim3(32, 8), 0, stream>>>(
        w1, W1T, M_DIM, F_DIM);
    transpose_cvt<<<dim3(M_DIM / 32, F_DIM / 32, E_NUM), dim3(32, 8), 0, stream>>>(
        w2, W2T, F_DIM, M_DIM);

    // GEMM1: H = gelu(A1 @ w1 + b1)   [E][C=1024][F=4096], K=M=1024
    gemm_bf16<0><<<E_NUM * (CAP / 128) * (F_DIM / 128), 256, 0, stream>>>(
        A1, W1T, b1, nullptr, H, nullptr, nullptr,
        M_DIM, CAP, F_DIM, CAP / 128, F_DIM / 128);

    // GEMM2: out[s] = gate[s] * (H @ w2 + b2)  scatter, K=F=4096
    gemm_bf16<1><<<E_NUM * (CAP / 128) * (M_DIM / 128), 256, 0, stream>>>(
        H, W2T, b2, out, nullptr, srcm, gate,
        F_DIM, CAP, M_DIM, CAP / 128, M_DIM / 128);
}

// Round 3
// 341.802 us; speedup vs baseline: 1.1586x; 1.0995x over previous
//
#include <hip/hip_runtime.h>
#include <hip/hip_bf16.h>
#include <math.h>

#define S_TOK 8192
#define M_DIM 1024
#define E_NUM 8
#define F_DIM 4096
#define CAP   1024

typedef short short8 __attribute__((ext_vector_type(8)));
typedef float f32x4 __attribute__((ext_vector_type(4)));
typedef unsigned short ushortx4 __attribute__((ext_vector_type(4)));

__device__ inline unsigned short f2bf(float f) {
    union { float f; unsigned int u; } v; v.f = f;
    unsigned int r = v.u + 0x7fffu + ((v.u >> 16) & 1u);
    return (unsigned short)(r >> 16);
}

// gelu(x) = 0.5 x (1 + tanh(y)), y = c(x + 0.044715 x^3) = x*e/(e+1), e=exp(2y)
__device__ inline float gelu_fast(float x) {
    float y = 0.7978845608028654f * (x + 0.044715f * x * x * x);
    if (y > 40.f) return x;
    float e = exp2f(2.8853900817779268f * y);
    return x * e / (e + 1.0f);
}

__device__ inline void gl_lds16(const void* g, void* l) {
    __builtin_amdgcn_global_load_lds(
        (const __attribute__((address_space(1))) unsigned int*)g,
        (__attribute__((address_space(3))) unsigned int*)l, 16, 0, 0);
}

// ---------------- gating ----------------
__global__ __launch_bounds__(256) void gating_kernel(
    const float* __restrict__ x, const float* __restrict__ wg,
    int* __restrict__ idx, float* __restrict__ gate)
{
    int wid = threadIdx.x >> 6;
    int lane = threadIdx.x & 63;
    int s = blockIdx.x * 4 + wid;
    const float* xs = x + (size_t)s * M_DIM;

    double acc[E_NUM];
#pragma unroll
    for (int e = 0; e < E_NUM; e++) acc[e] = 0.0;

    for (int i = lane; i < M_DIM; i += 64) {
        float xv = xs[i];
        float4 wa = *(const float4*)(wg + (size_t)i * E_NUM);
        float4 wb = *(const float4*)(wg + (size_t)i * E_NUM + 4);
        acc[0] += (double)xv * (double)wa.x;
        acc[1] += (double)xv * (double)wa.y;
        acc[2] += (double)xv * (double)wa.z;
        acc[3] += (double)xv * (double)wa.w;
        acc[4] += (double)xv * (double)wb.x;
        acc[5] += (double)xv * (double)wb.y;
        acc[6] += (double)xv * (double)wb.z;
        acc[7] += (double)xv * (double)wb.w;
    }
#pragma unroll
    for (int e = 0; e < E_NUM; e++) {
        double v = acc[e];
        for (int o = 32; o > 0; o >>= 1) v += __shfl_down(v, o, 64);
        acc[e] = v;
    }
    if (lane == 0) {
        double mx = acc[0]; int am = 0;
#pragma unroll
        for (int e = 1; e < E_NUM; e++) {
            if (acc[e] > mx) { mx = acc[e]; am = e; }
        }
        double se = 0.0;
#pragma unroll
        for (int e = 0; e < E_NUM; e++) se += exp(acc[e] - mx);
        idx[s] = am;
        gate[s] = (float)(1.0 / se);
    }
}

// ---------------- scan: token-order slot assignment ----------------
__global__ __launch_bounds__(1024) void scan_build(
    const int* __restrict__ idx, int* __restrict__ srcmap)
{
    __shared__ unsigned int sc[2][4][1024];
    int t = threadIdx.x;

    for (int i = t; i < E_NUM * CAP; i += 1024) srcmap[i] = -1;

    int eid[8];
    unsigned int cnt[E_NUM];
#pragma unroll
    for (int e = 0; e < E_NUM; e++) cnt[e] = 0;
#pragma unroll
    for (int i = 0; i < 8; i++) {
        int e = idx[t * 8 + i];
        eid[i] = e;
        cnt[e]++;
    }
    unsigned int pk[4];
#pragma unroll
    for (int i = 0; i < 4; i++) pk[i] = cnt[2 * i] | (cnt[2 * i + 1] << 16);
#pragma unroll
    for (int i = 0; i < 4; i++) sc[0][i][t] = pk[i];

    int buf = 0;
    for (int ofs = 1; ofs < 1024; ofs <<= 1) {
        __syncthreads();
        unsigned int v[4];
#pragma unroll
        for (int i = 0; i < 4; i++) {
            v[i] = sc[buf][i][t] + ((t >= ofs) ? sc[buf][i][t - ofs] : 0u);
            sc[buf ^ 1][i][t] = v[i];
        }
        buf ^= 1;
    }
    __syncthreads();
    unsigned int pos[E_NUM];
#pragma unroll
    for (int e = 0; e < E_NUM; e++) {
        unsigned int incl = (sc[buf][e >> 1][t] >> ((e & 1) * 16)) & 0xffffu;
        pos[e] = incl - cnt[e];
    }
#pragma unroll
    for (int i = 0; i < 8; i++) {
        int e = eid[i];
        unsigned int p = pos[e]++;
        if (p < CAP) srcmap[e * CAP + p] = t * 8 + i;
    }
}

// ---------------- dispatch: gather rows -> bf16 A1 [E*C][M] ----------------
__global__ __launch_bounds__(256) void dispatch_kernel(
    const float* __restrict__ x, const int* __restrict__ srcmap,
    unsigned short* __restrict__ A1)
{
    int slot = blockIdx.x;
    int s = srcmap[slot];
    int t = threadIdx.x;
    ushortx4 o;
    if (s >= 0) {
        float4 v = ((const float4*)(x + (size_t)s * M_DIM))[t];
        o[0] = f2bf(v.x); o[1] = f2bf(v.y); o[2] = f2bf(v.z); o[3] = f2bf(v.w);
    } else {
        o[0] = 0; o[1] = 0; o[2] = 0; o[3] = 0;
    }
    ((ushortx4*)(A1 + (size_t)slot * M_DIM))[t] = o;
}

// ---------------- transpose + cvt ----------------
__global__ __launch_bounds__(256) void transpose_cvt(
    const float* __restrict__ in, unsigned short* __restrict__ out, int R, int Cc)
{
    __shared__ float tile[32][33];
    int e = blockIdx.z;
    int br = blockIdx.y * 32, bc = blockIdx.x * 32;
    const float* ine = in + (size_t)e * R * Cc;
    unsigned short* oute = out + (size_t)e * R * Cc;
    int tx = threadIdx.x, ty = threadIdx.y;
#pragma unroll
    for (int i = 0; i < 32; i += 8)
        tile[ty + i][tx] = ine[(size_t)(br + ty + i) * Cc + (bc + tx)];
    __syncthreads();
#pragma unroll
    for (int i = 0; i < 32; i += 8)
        oute[(size_t)(bc + ty + i) * R + (br + tx)] = f2bf(tile[tx][ty + i]);
}

// ---------------- 256x256 deep-pipelined bf16 MFMA GEMM ----------------
// 8 waves (2Mx4N), BK=32, 4-slot LDS ring, counted vmcnt(8), XOR-swizzled LDS.
// A: [E][1024][K] bf16, B: [E][NB][K] bf16 (B^T layout).
// MODE 0 (GEMM1): K=1024, NB=4096. OutH = bf16(gelu(acc + bias)).
// MODE 1 (GEMM2): K=4096(split 2x2048), NB=1024. OutP[slice] = acc (f32 partial).
template <int MODE>
__global__ __launch_bounds__(512, 1) void gemm256(
    const unsigned short* __restrict__ A, const unsigned short* __restrict__ B,
    const float* __restrict__ bias, unsigned short* __restrict__ OutH,
    float* __restrict__ OutP)
{
    constexpr int K   = (MODE == 0) ? 1024 : 4096;
    constexpr int NB  = (MODE == 0) ? 4096 : 1024;
    constexpr int NT  = (MODE == 0) ? 32 : 64;   // K-tiles of 32 per block
    constexpr int NWG = (MODE == 0) ? 512 : 256;

    __shared__ unsigned short Asm[4 * 8192];   // 4 slots x 256 rows x 32 bf16
    __shared__ unsigned short Bsm[4 * 8192];

    // XCD-aware swizzle (nwg % 8 == 0)
    int bid = blockIdx.x;
    int swz = (bid & 7) * (NWG / 8) + (bid >> 3);
    int e, tm, tn, ks, kOff;
    if (MODE == 0) {
        e = swz >> 6; int rem = swz & 63; tm = rem >> 4; tn = rem & 15; ks = 0; kOff = 0;
    } else {
        ks = swz & 1; int q = swz >> 1; e = q >> 4; int rem = q & 15;
        tm = rem >> 2; tn = rem & 3; kOff = ks * 2048;
    }

    const unsigned short* Ae = A + ((size_t)e * CAP + (size_t)tm * 256) * K;
    const unsigned short* Be = B + ((size_t)e * NB + (size_t)tn * 256) * K;

    int tid = threadIdx.x;
    int wid = tid >> 6, lane = tid & 63;
    int wm = wid >> 2, wn = wid & 3;          // wave tile: rows wm*128, cols wn*64
    int fr = lane & 15, kq = lane >> 4;
    int swc = ((kq ^ ((fr >> 1) & 3)) << 3);  // swizzled chunk (elem offset) for ds_read

    // staging: thread covers row rr (+128 for round 1), global chunk cg pre-swizzled
    int rr = tid >> 2;
    int cg = (tid & 3) ^ ((rr >> 1) & 3);
    const unsigned short* srcA0 = Ae + (size_t)rr * K + kOff + cg * 8;
    const unsigned short* srcA1 = srcA0 + (size_t)128 * K;
    const unsigned short* srcB0 = Be + (size_t)rr * K + kOff + cg * 8;
    const unsigned short* srcB1 = srcB0 + (size_t)128 * K;
    unsigned short* ldsA = Asm + wid * 512;   // wave-uniform; HW adds lane*16B
    unsigned short* ldsB = Bsm + wid * 512;

#define STG_A(t_) do { int sl_ = ((t_) & 3) * 8192; int kk_ = (t_) * 32;          \
    gl_lds16(srcA0 + kk_, ldsA + sl_); gl_lds16(srcA1 + kk_, ldsA + sl_ + 4096); } while (0)
#define STG_B(t_) do { int sl_ = ((t_) & 3) * 8192; int kk_ = (t_) * 32;          \
    gl_lds16(srcB0 + kk_, ldsB + sl_); gl_lds16(srcB1 + kk_, ldsB + sl_ + 4096); } while (0)

    f32x4 acc[8][4];
#pragma unroll
    for (int i = 0; i < 8; i++)
#pragma unroll
        for (int j = 0; j < 4; j++) acc[i][j] = (f32x4){0.f, 0.f, 0.f, 0.f};

    // prologue: stage tiles 0,1,2 (12 loads in flight per wave)
    STG_A(0); STG_B(0); STG_A(1); STG_B(1); STG_A(2); STG_B(2);

    int arow = wm * 128 + fr;
    int brow = wn * 64 + fr;

    for (int t = 0; t < NT; ++t) {
        int sl = (t & 3) * 8192;
        int rem = NT - 1 - t;
        // drain tile t's loads (ours + everyone's via barrier); keep t+1,t+2 in flight
        if (rem > 1)       asm volatile("s_waitcnt vmcnt(8)" ::: "memory");
        else if (rem == 1) asm volatile("s_waitcnt vmcnt(4)" ::: "memory");
        else               asm volatile("s_waitcnt vmcnt(0)" ::: "memory");
        asm volatile("s_barrier" ::: "memory");

        // phase A: issue A-half of tile t+3, read a0-3 + b0-3, 16 MFMA
        if (t + 3 < NT) STG_A(t + 3);
        short8 a[4], b[4];
#pragma unroll
        for (int mi = 0; mi < 4; mi++)
            a[mi] = *(const short8*)&Asm[sl + (arow + mi * 16) * 32 + swc];
#pragma unroll
        for (int ni = 0; ni < 4; ni++)
            b[ni] = *(const short8*)&Bsm[sl + (brow + ni * 16) * 32 + swc];
        __builtin_amdgcn_s_setprio(1);
#pragma unroll
        for (int mi = 0; mi < 4; mi++)
#pragma unroll
            for (int ni = 0; ni < 4; ni++)
                acc[mi][ni] = __builtin_amdgcn_mfma_f32_16x16x32_bf16(
                    a[mi], b[ni], acc[mi][ni], 0, 0, 0);
        __builtin_amdgcn_s_setprio(0);

        // phase B: issue B-half of tile t+3, read a4-7, 16 MFMA
        if (t + 3 < NT) STG_B(t + 3);
#pragma unroll
        for (int mi = 0; mi < 4; mi++)
            a[mi] = *(const short8*)&Asm[sl + (arow + (mi + 4) * 16) * 32 + swc];
        __builtin_amdgcn_s_setprio(1);
#pragma unroll
        for (int mi = 0; mi < 4; mi++)
#pragma unroll
            for (int ni = 0; ni < 4; ni++)
                acc[mi + 4][ni] = __builtin_amdgcn_mfma_f32_16x16x32_bf16(
                    a[mi], b[ni], acc[mi + 4][ni], 0, 0, 0);
        __builtin_amdgcn_s_setprio(0);
    }
#undef STG_A
#undef STG_B

    int orow = kq * 4, ocol = fr;
    int cbase = tn * 256 + wn * 64;
    if (MODE == 0) {
        float bv[4];
#pragma unroll
        for (int ni = 0; ni < 4; ni++) bv[ni] = bias[e * NB + cbase + ni * 16 + ocol];
#pragma unroll
        for (int mi = 0; mi < 8; mi++) {
#pragma unroll
            for (int j = 0; j < 4; j++) {
                int r = tm * 256 + wm * 128 + mi * 16 + orow + j;
                size_t rowbase = ((size_t)e * CAP + r) * NB + cbase;
#pragma unroll
                for (int ni = 0; ni < 4; ni++)
                    OutH[rowbase + ni * 16 + ocol] = f2bf(gelu_fast(acc[mi][ni][j] + bv[ni]));
            }
        }
    } else {
        float* OP = OutP + (size_t)ks * S_TOK * M_DIM;
#pragma unroll
        for (int mi = 0; mi < 8; mi++) {
#pragma unroll
            for (int j = 0; j < 4; j++) {
                int r = tm * 256 + wm * 128 + mi * 16 + orow + j;
                size_t rowbase = ((size_t)e * CAP + r) * NB + cbase;
#pragma unroll
                for (int ni = 0; ni < 4; ni++)
                    OP[rowbase + ni * 16 + ocol] = acc[mi][ni][j];
            }
        }
    }
}

// ---------------- combine: out[s] = gate[s]*(P0[r]+P1[r]+b2[e]) ----------------
__global__ __launch_bounds__(256) void combine_kernel(
    const float* __restrict__ P, const int* __restrict__ srcmap,
    const float* __restrict__ gate, const float* __restrict__ b2,
    float* __restrict__ out)
{
    int r = blockIdx.x;
    int s = srcmap[r];
    if (s < 0) return;
    int e = r >> 10;
    float g = gate[s];
    int t = threadIdx.x;
    float4 p0 = ((const float4*)P)[r * 256 + t];
    float4 p1 = ((const float4*)(P + (size_t)S_TOK * M_DIM))[r * 256 + t];
    float4 bb = ((const float4*)b2)[e * 256 + t];
    float4 o;
    o.x = g * (p0.x + p1.x + bb.x);
    o.y = g * (p0.y + p1.y + bb.y);
    o.z = g * (p0.z + p1.z + bb.z);
    o.w = g * (p0.w + p1.w + bb.w);
    ((float4*)out)[s * 256 + t] = o;
}

extern "C" void kernel_launch(void* const* d_in, const int* in_sizes, int n_in,
                              void* d_out, int out_size, void* d_ws, size_t ws_size,
                              hipStream_t stream) {
    const float* x  = (const float*)d_in[0];  // [S, M]
    const float* wg = (const float*)d_in[1];  // [M, E]
    const float* w1 = (const float*)d_in[2];  // [E, M, F]
    const float* b1 = (const float*)d_in[3];  // [E, F]
    const float* w2 = (const float*)d_in[4];  // [E, F, M]
    const float* b2 = (const float*)d_in[5];  // [E, M]
    float* out = (float*)d_out;

    char* ws = (char*)d_ws;
    unsigned short* A1  = (unsigned short*)(ws);                       // 16 MiB [E*C][M]
    unsigned short* W1T = (unsigned short*)(ws + (size_t)(16u << 20)); // 64 MiB [E][F][M]
    float*          P   = (float*)(ws + (size_t)(16u << 20));          // 64 MiB (overlays W1T; GEMM2 phase)
    unsigned short* W2T = (unsigned short*)(ws + (size_t)(80u << 20)); // 64 MiB [E][M][F]
    unsigned short* H   = (unsigned short*)(ws + (size_t)(144u << 20));// 64 MiB [E][C][F]
    int*   idx  = (int*)(ws + (size_t)(208u << 20));
    float* gate = (float*)(ws + (size_t)(208u << 20) + 32768);
    int*   srcm = (int*)(ws + (size_t)(208u << 20) + 65536);

    hipMemsetAsync(d_out, 0, (size_t)S_TOK * M_DIM * sizeof(float), stream);

    gating_kernel<<<S_TOK / 4, 256, 0, stream>>>(x, wg, idx, gate);
    scan_build<<<1, 1024, 0, stream>>>(idx, srcm);
    dispatch_kernel<<<E_NUM * CAP, 256, 0, stream>>>(x, srcm, A1);
    transpose_cvt<<<dim3(F_DIM / 32, M_DIM / 32, E_NUM), dim3(32, 8), 0, stream>>>(
        w1, W1T, M_DIM, F_DIM);
    transpose_cvt<<<dim3(M_DIM / 32, F_DIM / 32, E_NUM), dim3(32, 8), 0, stream>>>(
        w2, W2T, F_DIM, M_DIM);

    // GEMM1: H = gelu(A1 @ w1 + b1)  [E][1024][4096], K=1024; 512 blocks
    gemm256<0><<<512, 512, 0, stream>>>(A1, W1T, b1, H, nullptr);

    // GEMM2: P[ks] = H @ w2 (split-K over 2 slices of 2048); 256 blocks
    gemm256<1><<<256, 512, 0, stream>>>(H, W2T, nullptr, nullptr, P);

    // combine: out[s] = gate[s]*(P0+P1+b2), scatter via srcmap
    combine_kernel<<<E_NUM * CAP, 256, 0, stream>>>(P, srcm, gate, b2, out);
}